// Round 2
// baseline (915.642 us; speedup 1.0000x reference)
//
#include <hip/hip_runtime.h>
#include <math.h>

#define HIDDEN 128
#define HEADS 8
#define HDIM 16

// ================= GEMM: C[rows,128] = A[rows,128] @ W[128,128] (+bias) =========
// Tile: 32 rows x 128 cols per block, 128 threads, each thread 8 rows x 4 cols.
__global__ __launch_bounds__(128) void gemm128(const float* __restrict__ A,
                                               const float* __restrict__ W,
                                               const float* __restrict__ bias,
                                               float* __restrict__ C, int rows) {
    __shared__ float As[32 * 128];
    const int tid = threadIdx.x;
    const int row0 = blockIdx.x * 32;

    const float4* A4 = reinterpret_cast<const float4*>(A);
    float4* As4 = reinterpret_cast<float4*>(As);
#pragma unroll
    for (int i = 0; i < 8; ++i) {
        int idx4 = tid + i * 128;      // 0..1023 (32 rows * 32 float4)
        int r = idx4 >> 5;
        float4 val = make_float4(0.f, 0.f, 0.f, 0.f);
        if (row0 + r < rows) val = A4[(size_t)(row0 + r) * 32 + (idx4 & 31)];
        As4[idx4] = val;
    }
    __syncthreads();

    const int c0 = (tid & 31) * 4;     // column group
    const int r0 = (tid >> 5) * 8;     // row group
    float acc[8][4];
#pragma unroll
    for (int i = 0; i < 8; ++i)
#pragma unroll
        for (int j = 0; j < 4; ++j) acc[i][j] = 0.f;

#pragma unroll 4
    for (int k = 0; k < 128; ++k) {
        const float4 w4 = *reinterpret_cast<const float4*>(&W[k * 128 + c0]);
#pragma unroll
        for (int i = 0; i < 8; ++i) {
            float a = As[(r0 + i) * 128 + k];
            acc[i][0] = fmaf(a, w4.x, acc[i][0]);
            acc[i][1] = fmaf(a, w4.y, acc[i][1]);
            acc[i][2] = fmaf(a, w4.z, acc[i][2]);
            acc[i][3] = fmaf(a, w4.w, acc[i][3]);
        }
    }

    float4 b4 = make_float4(0.f, 0.f, 0.f, 0.f);
    if (bias) b4 = *reinterpret_cast<const float4*>(&bias[c0]);
#pragma unroll
    for (int i = 0; i < 8; ++i) {
        int r = row0 + r0 + i;
        if (r < rows) {
            float4 o;
            o.x = acc[i][0] + b4.x;
            o.y = acc[i][1] + b4.y;
            o.z = acc[i][2] + b4.z;
            o.w = acc[i][3] + b4.w;
            reinterpret_cast<float4*>(C)[(size_t)r * 32 + (c0 >> 2)] = o;
        }
    }
}

// ================= CSR build =====================================================
__global__ void hist_kernel(const int* __restrict__ dst, int* __restrict__ deg, int E) {
    int i = blockIdx.x * blockDim.x + threadIdx.x;
    if (i < E) atomicAdd(&deg[dst[i]], 1);
}

__global__ void scan_blocks(const int* __restrict__ deg, int* __restrict__ incl,
                            int* __restrict__ bsum, int N) {
    __shared__ int s[256];
    int i = blockIdx.x * 256 + threadIdx.x;
    int vdeg = (i < N) ? deg[i] : 0;
    s[threadIdx.x] = vdeg;
    __syncthreads();
    for (int off = 1; off < 256; off <<= 1) {
        int t = (threadIdx.x >= off) ? s[threadIdx.x - off] : 0;
        __syncthreads();
        s[threadIdx.x] += t;
        __syncthreads();
    }
    if (i < N) incl[i] = s[threadIdx.x];
    if (threadIdx.x == 255) bsum[blockIdx.x] = s[255];
}

__global__ void scan_bsum(const int* __restrict__ bsum, int* __restrict__ boff, int nblk) {
    if (blockIdx.x == 0 && threadIdx.x == 0) {
        int run = 0;
        for (int i = 0; i < nblk; ++i) { boff[i] = run; run += bsum[i]; }
    }
}

__global__ void scan_finalize(const int* __restrict__ incl, const int* __restrict__ deg,
                              const int* __restrict__ boff, int* __restrict__ row_start, int N) {
    int i = blockIdx.x * 256 + threadIdx.x;
    if (i < N) row_start[i] = incl[i] - deg[i] + boff[blockIdx.x];
}

__global__ void scatter_kernel(const int* __restrict__ dst, const int* __restrict__ row_start,
                               int* __restrict__ cursor, int* __restrict__ perm, int E) {
    int i = blockIdx.x * blockDim.x + threadIdx.x;
    if (i < E) {
        int d = dst[i];
        int pos = row_start[d] + atomicAdd(&cursor[d], 1);
        perm[pos] = i;
    }
}

// ================= Fused per-node attention + beta gate + LN + residual ==========
__device__ __forceinline__ float block_reduce_sum_128(float val, float* red) {
#pragma unroll
    for (int off = 32; off > 0; off >>= 1) val += __shfl_xor(val, off, 64);
    int wave = threadIdx.x >> 6;
    if ((threadIdx.x & 63) == 0) red[wave] = val;
    __syncthreads();
    float r = red[0] + red[1];
    __syncthreads();
    return r;
}

__global__ __launch_bounds__(128) void node_fused(
    const float* __restrict__ q, const float* __restrict__ kbuf,
    const float* __restrict__ vbuf, const float* __restrict__ ebuf,
    const float* __restrict__ xr, const float* __restrict__ x_in,
    const int* __restrict__ perm, const int* __restrict__ row_start,
    const int* __restrict__ deg, const int* __restrict__ srcIdx,
    const float* __restrict__ Wb, const float* __restrict__ ln_g,
    const float* __restrict__ ln_b, float* __restrict__ out, int N) {
    __shared__ float red[2];
    const int n = blockIdx.x;
    const int tid = threadIdx.x;

    const float qv = q[(size_t)n * HIDDEN + tid];
    const int start = row_start[n];
    const int cnt = deg[n];

    float m = -INFINITY, z = 0.f, acc = 0.f;
    for (int i = 0; i < cnt; ++i) {
        const int eid = perm[start + i];
        const int s = srcIdx[eid];
        const float ev = ebuf[(size_t)eid * HIDDEN + tid];
        const float ke = kbuf[(size_t)s * HIDDEN + tid] + ev;
        const float ve = vbuf[(size_t)s * HIDDEN + tid] + ev;
        // per-head dot product over 16 lanes
        float p = qv * ke;
        p += __shfl_xor(p, 1, 16);
        p += __shfl_xor(p, 2, 16);
        p += __shfl_xor(p, 4, 16);
        p += __shfl_xor(p, 8, 16);
        const float alpha = p * 0.25f;  // / sqrt(16)
        const float mn = fmaxf(m, alpha);
        const float sc = __expf(m - mn);   // first iter: exp(-inf)=0
        const float w = __expf(alpha - mn);
        z = z * sc + w;
        acc = acc * sc + w * ve;
        m = mn;
    }
    float out_c = (z > 0.f) ? (acc / z) : 0.f;

    // beta gate: sigmoid([out, x_r, out-x_r] @ Wbeta)
    const float x_r_c = xr[(size_t)n * HIDDEN + tid];
    float g = out_c * Wb[tid] + x_r_c * Wb[HIDDEN + tid] + (out_c - x_r_c) * Wb[2 * HIDDEN + tid];
    float logit = block_reduce_sum_128(g, red);
    float beta = 1.f / (1.f + __expf(-logit));
    float o2 = beta * x_r_c + (1.f - beta) * out_c;

    // LayerNorm over 128 channels
    float mean = block_reduce_sum_128(o2, red) * (1.f / 128.f);
    float diff = o2 - mean;
    float var = block_reduce_sum_128(diff * diff, red) * (1.f / 128.f);
    float y = diff * rsqrtf(var + 1e-5f) * ln_g[tid] + ln_b[tid];

    out[(size_t)n * HIDDEN + tid] = x_in[(size_t)n * HIDDEN + tid] + fmaxf(y, 0.f);
}

// Fallback: workspace too small — emit zeros so the harness reports a clean
// validation failure (diagnostic) instead of an OOB-write container crash.
__global__ void zero_out_kernel(float* __restrict__ out, int n) {
    int i = blockIdx.x * blockDim.x + threadIdx.x;
    if (i < n) out[i] = 0.f;
}

// ================= launch ========================================================
extern "C" void kernel_launch(void* const* d_in, const int* in_sizes, int n_in,
                              void* d_out, int out_size, void* d_ws, size_t ws_size,
                              hipStream_t stream) {
    const float* edge_state = (const float*)d_in[0];
    const int* lg_edge_index = (const int*)d_in[1];
    const float* angle_emb = (const float*)d_in[2];
    const float* Wq = (const float*)d_in[3];
    const float* bq = (const float*)d_in[4];
    const float* Wk = (const float*)d_in[5];
    const float* bk = (const float*)d_in[6];
    const float* Wv = (const float*)d_in[7];
    const float* bv = (const float*)d_in[8];
    const float* We = (const float*)d_in[9];
    const float* Wskip = (const float*)d_in[10];
    const float* bskip = (const float*)d_in[11];
    const float* Wbeta = (const float*)d_in[12];
    const float* ln_g = (const float*)d_in[13];
    const float* ln_b = (const float*)d_in[14];

    const int N = in_sizes[0] / HIDDEN;
    const int E = in_sizes[1] / 2;
    const int* srcIdx = lg_edge_index;         // row 0 = message source j
    const int* dstIdx = lg_edge_index + E;     // row 1 = message target i

    // ---- workspace layout (all offsets 256B-aligned) ----
    char* ws = (char*)d_ws;
    size_t off = 0;
    auto alloc = [&](size_t bytes) { void* p = ws + off; off = (off + bytes + 255) & ~size_t(255); return p; };
    float* q   = (float*)alloc((size_t)N * HIDDEN * 4);
    float* k   = (float*)alloc((size_t)N * HIDDEN * 4);
    float* v   = (float*)alloc((size_t)N * HIDDEN * 4);
    float* xr  = (float*)alloc((size_t)N * HIDDEN * 4);
    float* e   = (float*)alloc((size_t)E * HIDDEN * 4);
    int* deg       = (int*)alloc((size_t)N * 4);
    int* cursor    = (int*)alloc((size_t)N * 4);
    int* row_start = (int*)alloc((size_t)N * 4);
    int* incl      = (int*)alloc((size_t)N * 4);
    int* perm      = (int*)alloc((size_t)E * 4);
    const int nblkScan = (N + 255) / 256;
    int* bsum = (int*)alloc((size_t)nblkScan * 4);
    int* boff = (int*)alloc((size_t)nblkScan * 4);

    // ---- workspace guard: never write past ws_size ----
    if (off > ws_size) {
        zero_out_kernel<<<(out_size + 255) / 256, 256, 0, stream>>>((float*)d_out, out_size);
        return;
    }

    // ---- dense projections (f32 vector GEMM; no fp32 MFMA on CDNA4) ----
    const int gN = (N + 31) / 32;
    const int gE = (E + 31) / 32;
    gemm128<<<gN, 128, 0, stream>>>(edge_state, Wq, bq, q, N);
    gemm128<<<gN, 128, 0, stream>>>(edge_state, Wk, bk, k, N);
    gemm128<<<gN, 128, 0, stream>>>(edge_state, Wv, bv, v, N);
    gemm128<<<gN, 128, 0, stream>>>(edge_state, Wskip, bskip, xr, N);
    gemm128<<<gE, 128, 0, stream>>>(angle_emb, We, nullptr, e, E);

    // ---- CSR build ----
    hipMemsetAsync(deg, 0, (size_t)N * 4, stream);
    hipMemsetAsync(cursor, 0, (size_t)N * 4, stream);
    const int eb = (E + 255) / 256;
    hist_kernel<<<eb, 256, 0, stream>>>(dstIdx, deg, E);
    scan_blocks<<<nblkScan, 256, 0, stream>>>(deg, incl, bsum, N);
    scan_bsum<<<1, 1, 0, stream>>>(bsum, boff, nblkScan);
    scan_finalize<<<nblkScan, 256, 0, stream>>>(incl, deg, boff, row_start, N);
    scatter_kernel<<<eb, 256, 0, stream>>>(dstIdx, row_start, cursor, perm, E);

    // ---- fused per-node attention + gate + LN + residual ----
    node_fused<<<N, 128, 0, stream>>>(q, k, v, e, xr, edge_state, perm, row_start,
                                      deg, srcIdx, Wbeta, ln_g, ln_b, (float*)d_out, N);
}

// Round 3
// 888.472 us; speedup vs baseline: 1.0306x; 1.0306x over previous
//
#include <hip/hip_runtime.h>
#include <math.h>

#define HIDDEN 128
#define HEADS 8
#define HDIM 16

// ======== Fused QKVS GEMM: 4 outputs share one A-tile ===========================
// Tile: 32 rows x 128 cols, 128 threads, each thread 8 rows x 4 cols.
// Inner loop k-unrolled by 4 with ds_read_b128 A-fragment reads.
__global__ __launch_bounds__(128) void gemm_qkvs(
    const float* __restrict__ A,
    const float* __restrict__ W0, const float* __restrict__ b0, float* __restrict__ C0,
    const float* __restrict__ W1, const float* __restrict__ b1, float* __restrict__ C1,
    const float* __restrict__ W2, const float* __restrict__ b2, float* __restrict__ C2,
    const float* __restrict__ W3, const float* __restrict__ b3, float* __restrict__ C3,
    int rows) {
    __shared__ float As[32 * 128];
    const int tid = threadIdx.x;
    const int row0 = blockIdx.x * 32;

    const float4* A4 = reinterpret_cast<const float4*>(A);
    float4* As4 = reinterpret_cast<float4*>(As);
#pragma unroll
    for (int i = 0; i < 8; ++i) {
        int idx4 = tid + i * 128;
        int r = idx4 >> 5;
        float4 val = make_float4(0.f, 0.f, 0.f, 0.f);
        if (row0 + r < rows) val = A4[(size_t)(row0 + r) * 32 + (idx4 & 31)];
        As4[idx4] = val;
    }
    __syncthreads();

    const int c0 = (tid & 31) * 4;
    const int r0 = (tid >> 5) * 8;

    const float* Ws[4] = {W0, W1, W2, W3};
    const float* bs[4] = {b0, b1, b2, b3};
    float* Cs[4] = {C0, C1, C2, C3};

    for (int w = 0; w < 4; ++w) {
        const float* __restrict__ W = Ws[w];
        float acc[8][4];
#pragma unroll
        for (int i = 0; i < 8; ++i)
#pragma unroll
            for (int j = 0; j < 4; ++j) acc[i][j] = 0.f;

#pragma unroll 2
        for (int k0 = 0; k0 < 128; k0 += 4) {
            const float4 w0 = *reinterpret_cast<const float4*>(&W[(k0 + 0) * 128 + c0]);
            const float4 w1 = *reinterpret_cast<const float4*>(&W[(k0 + 1) * 128 + c0]);
            const float4 w2 = *reinterpret_cast<const float4*>(&W[(k0 + 2) * 128 + c0]);
            const float4 w3 = *reinterpret_cast<const float4*>(&W[(k0 + 3) * 128 + c0]);
#pragma unroll
            for (int i = 0; i < 8; ++i) {
                const float4 a = As4[(r0 + i) * 32 + (k0 >> 2)];
                acc[i][0] = fmaf(a.x, w0.x, acc[i][0]);
                acc[i][1] = fmaf(a.x, w0.y, acc[i][1]);
                acc[i][2] = fmaf(a.x, w0.z, acc[i][2]);
                acc[i][3] = fmaf(a.x, w0.w, acc[i][3]);
                acc[i][0] = fmaf(a.y, w1.x, acc[i][0]);
                acc[i][1] = fmaf(a.y, w1.y, acc[i][1]);
                acc[i][2] = fmaf(a.y, w1.z, acc[i][2]);
                acc[i][3] = fmaf(a.y, w1.w, acc[i][3]);
                acc[i][0] = fmaf(a.z, w2.x, acc[i][0]);
                acc[i][1] = fmaf(a.z, w2.y, acc[i][1]);
                acc[i][2] = fmaf(a.z, w2.z, acc[i][2]);
                acc[i][3] = fmaf(a.z, w2.w, acc[i][3]);
                acc[i][0] = fmaf(a.w, w3.x, acc[i][0]);
                acc[i][1] = fmaf(a.w, w3.y, acc[i][1]);
                acc[i][2] = fmaf(a.w, w3.z, acc[i][2]);
                acc[i][3] = fmaf(a.w, w3.w, acc[i][3]);
            }
        }

        const float4 b4 = *reinterpret_cast<const float4*>(&bs[w][c0]);
#pragma unroll
        for (int i = 0; i < 8; ++i) {
            int r = row0 + r0 + i;
            if (r < rows) {
                float4 o;
                o.x = acc[i][0] + b4.x;
                o.y = acc[i][1] + b4.y;
                o.z = acc[i][2] + b4.z;
                o.w = acc[i][3] + b4.w;
                reinterpret_cast<float4*>(Cs[w])[(size_t)r * 32 + (c0 >> 2)] = o;
            }
        }
    }
}

// ======== e-GEMM with scatter-to-CSR-order output ================================
// C_sorted[inv_perm[r]] = A[r] @ W   (no bias)
__global__ __launch_bounds__(128) void gemm_e_scatter(
    const float* __restrict__ A, const float* __restrict__ W,
    const int* __restrict__ inv_perm, float* __restrict__ C, int rows) {
    __shared__ float As[32 * 128];
    __shared__ int rowmap[32];
    const int tid = threadIdx.x;
    const int row0 = blockIdx.x * 32;

    if (tid < 32) {
        int r = row0 + tid;
        rowmap[tid] = (r < rows) ? inv_perm[r] : -1;
    }
    const float4* A4 = reinterpret_cast<const float4*>(A);
    float4* As4 = reinterpret_cast<float4*>(As);
#pragma unroll
    for (int i = 0; i < 8; ++i) {
        int idx4 = tid + i * 128;
        int r = idx4 >> 5;
        float4 val = make_float4(0.f, 0.f, 0.f, 0.f);
        if (row0 + r < rows) val = A4[(size_t)(row0 + r) * 32 + (idx4 & 31)];
        As4[idx4] = val;
    }
    __syncthreads();

    const int c0 = (tid & 31) * 4;
    const int r0 = (tid >> 5) * 8;
    float acc[8][4];
#pragma unroll
    for (int i = 0; i < 8; ++i)
#pragma unroll
        for (int j = 0; j < 4; ++j) acc[i][j] = 0.f;

#pragma unroll 2
    for (int k0 = 0; k0 < 128; k0 += 4) {
        const float4 w0 = *reinterpret_cast<const float4*>(&W[(k0 + 0) * 128 + c0]);
        const float4 w1 = *reinterpret_cast<const float4*>(&W[(k0 + 1) * 128 + c0]);
        const float4 w2 = *reinterpret_cast<const float4*>(&W[(k0 + 2) * 128 + c0]);
        const float4 w3 = *reinterpret_cast<const float4*>(&W[(k0 + 3) * 128 + c0]);
#pragma unroll
        for (int i = 0; i < 8; ++i) {
            const float4 a = As4[(r0 + i) * 32 + (k0 >> 2)];
            acc[i][0] = fmaf(a.x, w0.x, acc[i][0]);
            acc[i][1] = fmaf(a.x, w0.y, acc[i][1]);
            acc[i][2] = fmaf(a.x, w0.z, acc[i][2]);
            acc[i][3] = fmaf(a.x, w0.w, acc[i][3]);
            acc[i][0] = fmaf(a.y, w1.x, acc[i][0]);
            acc[i][1] = fmaf(a.y, w1.y, acc[i][1]);
            acc[i][2] = fmaf(a.y, w1.z, acc[i][2]);
            acc[i][3] = fmaf(a.y, w1.w, acc[i][3]);
            acc[i][0] = fmaf(a.z, w2.x, acc[i][0]);
            acc[i][1] = fmaf(a.z, w2.y, acc[i][1]);
            acc[i][2] = fmaf(a.z, w2.z, acc[i][2]);
            acc[i][3] = fmaf(a.z, w2.w, acc[i][3]);
            acc[i][0] = fmaf(a.w, w3.x, acc[i][0]);
            acc[i][1] = fmaf(a.w, w3.y, acc[i][1]);
            acc[i][2] = fmaf(a.w, w3.z, acc[i][2]);
            acc[i][3] = fmaf(a.w, w3.w, acc[i][3]);
        }
    }

#pragma unroll
    for (int i = 0; i < 8; ++i) {
        int r = row0 + r0 + i;
        if (r < rows) {
            int tr = rowmap[r0 + i];
            float4 o;
            o.x = acc[i][0];
            o.y = acc[i][1];
            o.z = acc[i][2];
            o.w = acc[i][3];
            reinterpret_cast<float4*>(C)[(size_t)tr * 32 + (c0 >> 2)] = o;
        }
    }
}

// ================= CSR build =====================================================
__global__ void hist_kernel(const int* __restrict__ dst, int* __restrict__ deg, int E) {
    int i = blockIdx.x * blockDim.x + threadIdx.x;
    if (i < E) atomicAdd(&deg[dst[i]], 1);
}

__global__ void scan_blocks(const int* __restrict__ deg, int* __restrict__ incl,
                            int* __restrict__ bsum, int N) {
    __shared__ int s[256];
    int i = blockIdx.x * 256 + threadIdx.x;
    int vdeg = (i < N) ? deg[i] : 0;
    s[threadIdx.x] = vdeg;
    __syncthreads();
    for (int off = 1; off < 256; off <<= 1) {
        int t = (threadIdx.x >= off) ? s[threadIdx.x - off] : 0;
        __syncthreads();
        s[threadIdx.x] += t;
        __syncthreads();
    }
    if (i < N) incl[i] = s[threadIdx.x];
    if (threadIdx.x == 255) bsum[blockIdx.x] = s[255];
}

__global__ void scan_bsum(const int* __restrict__ bsum, int* __restrict__ boff, int nblk) {
    if (blockIdx.x == 0 && threadIdx.x == 0) {
        int run = 0;
        for (int i = 0; i < nblk; ++i) { boff[i] = run; run += bsum[i]; }
    }
}

__global__ void scan_finalize(const int* __restrict__ incl, const int* __restrict__ deg,
                              const int* __restrict__ boff, int* __restrict__ row_start, int N) {
    int i = blockIdx.x * 256 + threadIdx.x;
    if (i < N) row_start[i] = incl[i] - deg[i] + boff[blockIdx.x];
}

// For each edge: pos = CSR slot; write inv_perm[edge]=pos and src_sorted[pos]=src[edge]
__global__ void build_kernel(const int* __restrict__ dst, const int* __restrict__ src,
                             const int* __restrict__ row_start, int* __restrict__ cursor,
                             int* __restrict__ inv_perm, int* __restrict__ src_sorted, int E) {
    int i = blockIdx.x * blockDim.x + threadIdx.x;
    if (i < E) {
        int d = dst[i];
        int pos = row_start[d] + atomicAdd(&cursor[d], 1);
        inv_perm[i] = pos;
        src_sorted[pos] = src[i];
    }
}

// ================= Fused per-node attention + beta gate + LN + residual ==========
__device__ __forceinline__ float block_reduce_sum_128(float val, float* red) {
#pragma unroll
    for (int off = 32; off > 0; off >>= 1) val += __shfl_xor(val, off, 64);
    int wave = threadIdx.x >> 6;
    if ((threadIdx.x & 63) == 0) red[wave] = val;
    __syncthreads();
    float r = red[0] + red[1];
    __syncthreads();
    return r;
}

__device__ __forceinline__ float head_dot16(float p) {
    p += __shfl_xor(p, 1, 16);
    p += __shfl_xor(p, 2, 16);
    p += __shfl_xor(p, 4, 16);
    p += __shfl_xor(p, 8, 16);
    return p;
}

__global__ __launch_bounds__(128) void node_fused(
    const float* __restrict__ q, const float* __restrict__ kbuf,
    const float* __restrict__ vbuf, const float* __restrict__ e_sorted,
    const float* __restrict__ xr, const float* __restrict__ x_in,
    const int* __restrict__ row_start, const int* __restrict__ deg,
    const int* __restrict__ src_sorted,
    const float* __restrict__ Wb, const float* __restrict__ ln_g,
    const float* __restrict__ ln_b, float* __restrict__ out, int N) {
    __shared__ float red[2];
    const int n = blockIdx.x;
    const int tid = threadIdx.x;

    const float qv = q[(size_t)n * HIDDEN + tid];
    const int start = row_start[n];
    const int cnt = deg[n];

    float m = -INFINITY, z = 0.f, acc = 0.f;
    int i = 0;
    // 2-edge unroll: independent load streams double memory-level parallelism
    for (; i + 2 <= cnt; i += 2) {
        const int p0 = start + i, p1 = start + i + 1;
        const int s0 = src_sorted[p0], s1 = src_sorted[p1];
        const float e0 = e_sorted[(size_t)p0 * HIDDEN + tid];
        const float e1 = e_sorted[(size_t)p1 * HIDDEN + tid];
        const float k0 = kbuf[(size_t)s0 * HIDDEN + tid] + e0;
        const float v0 = vbuf[(size_t)s0 * HIDDEN + tid] + e0;
        const float k1 = kbuf[(size_t)s1 * HIDDEN + tid] + e1;
        const float v1 = vbuf[(size_t)s1 * HIDDEN + tid] + e1;
        float d0 = head_dot16(qv * k0) * 0.25f;
        float d1 = head_dot16(qv * k1) * 0.25f;
        const float mn = fmaxf(m, fmaxf(d0, d1));
        const float sc = __expf(m - mn);
        const float w0 = __expf(d0 - mn);
        const float w1 = __expf(d1 - mn);
        z = z * sc + w0 + w1;
        acc = acc * sc + w0 * v0 + w1 * v1;
        m = mn;
    }
    if (i < cnt) {
        const int p0 = start + i;
        const int s0 = src_sorted[p0];
        const float e0 = e_sorted[(size_t)p0 * HIDDEN + tid];
        const float k0 = kbuf[(size_t)s0 * HIDDEN + tid] + e0;
        const float v0 = vbuf[(size_t)s0 * HIDDEN + tid] + e0;
        float d0 = head_dot16(qv * k0) * 0.25f;
        const float mn = fmaxf(m, d0);
        const float sc = __expf(m - mn);
        const float w0 = __expf(d0 - mn);
        z = z * sc + w0;
        acc = acc * sc + w0 * v0;
        m = mn;
    }
    float out_c = (z > 0.f) ? (acc / z) : 0.f;

    // beta gate: sigmoid([out, x_r, out-x_r] @ Wbeta)
    const float x_r_c = xr[(size_t)n * HIDDEN + tid];
    float g = out_c * Wb[tid] + x_r_c * Wb[HIDDEN + tid] + (out_c - x_r_c) * Wb[2 * HIDDEN + tid];
    float logit = block_reduce_sum_128(g, red);
    float beta = 1.f / (1.f + __expf(-logit));
    float o2 = beta * x_r_c + (1.f - beta) * out_c;

    // LayerNorm over 128 channels
    float mean = block_reduce_sum_128(o2, red) * (1.f / 128.f);
    float diff = o2 - mean;
    float var = block_reduce_sum_128(diff * diff, red) * (1.f / 128.f);
    float y = diff * rsqrtf(var + 1e-5f) * ln_g[tid] + ln_b[tid];

    out[(size_t)n * HIDDEN + tid] = x_in[(size_t)n * HIDDEN + tid] + fmaxf(y, 0.f);
}

// Fallback: workspace too small — clean validation failure instead of OOB crash.
__global__ void zero_out_kernel(float* __restrict__ out, int n) {
    int i = blockIdx.x * blockDim.x + threadIdx.x;
    if (i < n) out[i] = 0.f;
}

// ================= launch ========================================================
extern "C" void kernel_launch(void* const* d_in, const int* in_sizes, int n_in,
                              void* d_out, int out_size, void* d_ws, size_t ws_size,
                              hipStream_t stream) {
    const float* edge_state = (const float*)d_in[0];
    const int* lg_edge_index = (const int*)d_in[1];
    const float* angle_emb = (const float*)d_in[2];
    const float* Wq = (const float*)d_in[3];
    const float* bq = (const float*)d_in[4];
    const float* Wk = (const float*)d_in[5];
    const float* bk = (const float*)d_in[6];
    const float* Wv = (const float*)d_in[7];
    const float* bv = (const float*)d_in[8];
    const float* We = (const float*)d_in[9];
    const float* Wskip = (const float*)d_in[10];
    const float* bskip = (const float*)d_in[11];
    const float* Wbeta = (const float*)d_in[12];
    const float* ln_g = (const float*)d_in[13];
    const float* ln_b = (const float*)d_in[14];

    const int N = in_sizes[0] / HIDDEN;
    const int E = in_sizes[1] / 2;
    const int* srcIdx = lg_edge_index;         // row 0 = message source j
    const int* dstIdx = lg_edge_index + E;     // row 1 = message target i

    // ---- workspace layout (256B aligned) ----
    char* ws = (char*)d_ws;
    size_t off = 0;
    auto alloc = [&](size_t bytes) { void* p = ws + off; off = (off + bytes + 255) & ~size_t(255); return p; };
    float* q        = (float*)alloc((size_t)N * HIDDEN * 4);
    float* k        = (float*)alloc((size_t)N * HIDDEN * 4);
    float* v        = (float*)alloc((size_t)N * HIDDEN * 4);
    float* xr       = (float*)alloc((size_t)N * HIDDEN * 4);
    float* e_sorted = (float*)alloc((size_t)E * HIDDEN * 4);
    int* deg        = (int*)alloc((size_t)N * 4);
    int* cursor     = (int*)alloc((size_t)N * 4);
    int* row_start  = (int*)alloc((size_t)N * 4);
    int* incl       = (int*)alloc((size_t)N * 4);
    int* inv_perm   = (int*)alloc((size_t)E * 4);
    int* src_sorted = (int*)alloc((size_t)E * 4);
    const int nblkScan = (N + 255) / 256;
    int* bsum = (int*)alloc((size_t)nblkScan * 4);
    int* boff = (int*)alloc((size_t)nblkScan * 4);

    if (off > ws_size) {
        zero_out_kernel<<<(out_size + 255) / 256, 256, 0, stream>>>((float*)d_out, out_size);
        return;
    }

    // ---- CSR build first (e-GEMM needs inv_perm) ----
    hipMemsetAsync(deg, 0, (size_t)N * 4, stream);
    hipMemsetAsync(cursor, 0, (size_t)N * 4, stream);
    const int eb = (E + 255) / 256;
    hist_kernel<<<eb, 256, 0, stream>>>(dstIdx, deg, E);
    scan_blocks<<<nblkScan, 256, 0, stream>>>(deg, incl, bsum, N);
    scan_bsum<<<1, 1, 0, stream>>>(bsum, boff, nblkScan);
    scan_finalize<<<nblkScan, 256, 0, stream>>>(incl, deg, boff, row_start, N);
    build_kernel<<<eb, 256, 0, stream>>>(dstIdx, srcIdx, row_start, cursor,
                                         inv_perm, src_sorted, E);

    // ---- dense projections ----
    const int gN = (N + 31) / 32;
    const int gE = (E + 31) / 32;
    gemm_qkvs<<<gN, 128, 0, stream>>>(edge_state,
                                      Wq, bq, q, Wk, bk, k, Wv, bv, v, Wskip, bskip, xr, N);
    gemm_e_scatter<<<gE, 128, 0, stream>>>(angle_emb, We, inv_perm, e_sorted, E);

    // ---- fused per-node attention + gate + LN + residual ----
    node_fused<<<N, 128, 0, stream>>>(q, k, v, e_sorted, xr, edge_state, row_start,
                                      deg, src_sorted, Wbeta, ln_g, ln_b, (float*)d_out, N);
}